// Round 8
// baseline (330.325 us; speedup 1.0000x reference)
//
#include <hip/hip_runtime.h>

namespace {
constexpr int L_ = 512;
constexpr int B_ = 1024;
constexpr int K_ = 64;
constexpr int START_I = 62;
constexpr int STOP_I = 63;
}

typedef float f4 __attribute__((ext_vector_type(4)));
typedef float f32x4 __attribute__((ext_vector_type(4)));
typedef short short8v __attribute__((ext_vector_type(8)));
typedef unsigned int u32;
typedef unsigned int u32x2 __attribute__((ext_vector_type(2)));
typedef unsigned int u32x4 __attribute__((ext_vector_type(4)));

#define LOG2E 1.4426950408889634f
#define LN2 0.6931471805599453f

// f32 pair -> packed bf16 (low = first operand)
#define CVTPK(dst, x, y) \
    u32 dst; asm("v_cvt_pk_bf16_f32 %0, %1, %2" : "=v"(dst) : "v"(x), "v"(y));

// mfma over bf16 frags stored as u32x4 bit-patterns
#define MF(Au, Bv, Cv) \
    __builtin_amdgcn_mfma_f32_16x16x32_bf16( \
        __builtin_bit_cast(short8v, Au), (Bv), (Cv), 0, 0, 0)

#define EXP4(dst, src) \
    f4 dst = {exp2f((src).x * LOG2E), exp2f((src).y * LOG2E), \
              exp2f((src).z * LOG2E), exp2f((src).w * LOG2E)};

// One recursion step for 16 batches: P' = exp(emit_t) (.) (E*P), bf16 MFMA.
// RS*: emit ring slot (4 x f4, states 16T+4q..+3), reloaded for t+4.
// RECEN: per-column power-of-2 rescale via exponent of state 0.
#define STEP(RS0_, RS1_, RS2_, RS3_, TT, RECEN)                              \
    {                                                                        \
        const bool act = (TT) < lenj;                                        \
        EXP4(ee0, RS0_) EXP4(ee1, RS1_) EXP4(ee2, RS2_) EXP4(ee3, RS3_)      \
        {                                                                    \
            int tp = (TT) + 4; if (tp > lenj - 1) tp = lenj - 1;             \
            const float* pb = ep + (long)tp * (B_ * K_);                     \
            RS0_ = *(const f4*)(pb);      RS1_ = *(const f4*)(pb + 16);      \
            RS2_ = *(const f4*)(pb + 32); RS3_ = *(const f4*)(pb + 48);      \
        }                                                                    \
        short8v Bv0 = __builtin_bit_cast(short8v, (u32x4){b0, b1, b2, b3});  \
        short8v Bv1 = __builtin_bit_cast(short8v, (u32x4){b4, b5, b6, b7});  \
        f32x4 d0 = MF(A00u, Bv0, zf); d0 = MF(A01u, Bv1, d0);                \
        f32x4 d1 = MF(A10u, Bv0, zf); d1 = MF(A11u, Bv1, d1);                \
        f32x4 d2 = MF(A20u, Bv0, zf); d2 = MF(A21u, Bv1, d2);                \
        f32x4 d3 = MF(A30u, Bv0, zf); d3 = MF(A31u, Bv1, d3);                \
        d0 *= ee0; d1 *= ee1; d2 *= ee2; d3 *= ee3;                          \
        if (RECEN) {                                                         \
            int vi = __builtin_amdgcn_ds_bpermute(colAddr,                   \
                                                  __float_as_int(d0.x));     \
            int ke = ((vi >> 23) & 0xFF) - 127;                              \
            float scl = __uint_as_float((u32)(127 - ke) << 23);              \
            d0 *= scl; d1 *= scl; d2 *= scl; d3 *= scl;                      \
            base2 = act ? (base2 + (float)ke) : base2;                       \
        }                                                                    \
        CVTPK(p00, d0.x, d0.y) CVTPK(p01, d0.z, d0.w)                        \
        CVTPK(p10, d1.x, d1.y) CVTPK(p11, d1.z, d1.w)                        \
        CVTPK(p20, d2.x, d2.y) CVTPK(p21, d2.z, d2.w)                        \
        CVTPK(p30, d3.x, d3.y) CVTPK(p31, d3.z, d3.w)                        \
        *(u32x2*)(lds + w0) = (u32x2){p00, p01};                             \
        *(u32x2*)(lds + w1) = (u32x2){p10, p11};                             \
        *(u32x2*)(lds + w2) = (u32x2){p20, p21};                             \
        *(u32x2*)(lds + w3) = (u32x2){p30, p31};                             \
        __builtin_amdgcn_wave_barrier();                                     \
        u32x4 n0 = *(const u32x4*)(lds + r0);                                \
        u32x4 n1 = *(const u32x4*)(lds + r1);                                \
        __builtin_amdgcn_wave_barrier();                                     \
        b0 = act ? n0.x : b0; b1 = act ? n0.y : b1;                          \
        b2 = act ? n0.z : b2; b3 = act ? n0.w : b3;                          \
        b4 = act ? n1.x : b4; b5 = act ? n1.y : b5;                          \
        b6 = act ? n1.z : b6; b7 = act ? n1.w : b7;                          \
    }

__global__ __launch_bounds__(64)
__attribute__((amdgpu_waves_per_eu(1, 1)))
void crf_kernel(
    const float* __restrict__ emit,    // (L,B,K)
    const float* __restrict__ trans,   // (K,K)
    const int* __restrict__ labels,    // (L,B)
    const float* __restrict__ masks,   // (L,B)
    float* __restrict__ out)           // (B,)
{
    __shared__ __align__(16) u32 lds[16 * 32];
    const int lane = threadIdx.x & 63;
    const int j = lane & 15;          // batch col (B/D) == row-in-tile (A)
    const int q = lane >> 4;          // k-octet (A/B) == row quadrant (D)
    const int g0 = blockIdx.x << 4;
    const int gb = g0 + j;

    // ---- A-frags: E = exp(T), tile T rows 16T..16T+15, k-half h. ----
    // lane: row 16T + j, k = 32h + 8q + e (e=0..7). bf16 packed pairs.
#define MKAF(T, h, NAME)                                                     \
    u32x4 NAME;                                                              \
    {                                                                        \
        const float* er = trans + (16 * (T) + j) * K_ + 32 * (h) + 8 * q;    \
        float f0 = exp2f(er[0] * LOG2E), f1 = exp2f(er[1] * LOG2E);          \
        float f2 = exp2f(er[2] * LOG2E), f3 = exp2f(er[3] * LOG2E);          \
        float f4_ = exp2f(er[4] * LOG2E), f5 = exp2f(er[5] * LOG2E);         \
        float f6 = exp2f(er[6] * LOG2E), f7 = exp2f(er[7] * LOG2E);          \
        CVTPK(c0, f0, f1) CVTPK(c1, f2, f3)                                  \
        CVTPK(c2, f4_, f5) CVTPK(c3, f6, f7)                                 \
        asm("" : "+v"(c0), "+v"(c1), "+v"(c2), "+v"(c3));                    \
        NAME = (u32x4){c0, c1, c2, c3};                                      \
    }
    MKAF(0, 0, A00u) MKAF(0, 1, A01u)
    MKAF(1, 0, A10u) MKAF(1, 1, A11u)
    MKAF(2, 0, A20u) MKAF(2, 1, A21u)
    MKAF(3, 0, A30u) MKAF(3, 1, A31u)
#undef MKAF

    // ---- len per column (masks are prefix masks). Lane covers its col's
    // quarter of t; reduce across the column's 4 lanes. ----
    int len = 0;
    for (int tt = 0; tt < 128; ++tt)
        len += (int)masks[(128 * q + tt) * B_ + gb];
    len += __shfl_xor(len, 16);
    len += __shfl_xor(len, 32);
    const int lenj = len;
    int ml = lenj;
    ml = max(ml, __shfl_xor(ml, 1));
    ml = max(ml, __shfl_xor(ml, 2));
    ml = max(ml, __shfl_xor(ml, 4));
    ml = max(ml, __shfl_xor(ml, 8));
    const int ml4 = (ml + 3) & ~3;

    // ---- LDS shuffle addresses (word units). Slot word for state-pair sp
    // of column j: j*32 + (sp ^ ((j&7)<<2)); multiple-of-4 swizzle keeps
    // b64/b128 alignment+order and floors bank conflicts. ----
    const int swz = (j & 7) << 2;
    const int w0 = j * 32 + ((0 + 2 * q) ^ swz);
    const int w1 = j * 32 + ((8 + 2 * q) ^ swz);
    const int w2 = j * 32 + ((16 + 2 * q) ^ swz);
    const int w3 = j * 32 + ((24 + 2 * q) ^ swz);
    const int r0 = j * 32 + ((4 * q) ^ swz);
    const int r1 = j * 32 + ((16 + 4 * q) ^ swz);
    const int colAddr = j * 4;

    // ---- state: B-frags (bf16 pairs, k=32h+8q+e), one-hot START. ----
    u32 b0 = 0, b1 = 0, b2 = 0, b3 = 0, b4 = 0, b5 = 0, b6 = 0;
    u32 b7 = (q == 3) ? 0x00003F80u : 0u;   // state 62 = 32 + 8*3 + 6, low
    float base2 = 0.0f;
    const f32x4 zf = {0.f, 0.f, 0.f, 0.f};

    // ---- emit ring, depth 4: slot s holds t=s states 16T+4q..+3. ----
    const float* ep = emit + gb * K_ + 4 * q;
#define LDR(S)                                                               \
    f4 R##S##_0 = *(const f4*)(ep + (long)(S) * (B_ * K_));                  \
    f4 R##S##_1 = *(const f4*)(ep + (long)(S) * (B_ * K_) + 16);             \
    f4 R##S##_2 = *(const f4*)(ep + (long)(S) * (B_ * K_) + 32);             \
    f4 R##S##_3 = *(const f4*)(ep + (long)(S) * (B_ * K_) + 48);
    LDR(0) LDR(1) LDR(2) LDR(3)
#undef LDR

    for (int tg = 0; tg < ml4; tg += 4) {
        STEP(R0_0, R0_1, R0_2, R0_3, tg + 0, 0)
        STEP(R1_0, R1_1, R1_2, R1_3, tg + 1, 0)
        STEP(R2_0, R2_1, R2_2, R2_3, tg + 2, 0)
        STEP(R3_0, R3_1, R3_2, R3_3, tg + 3, 1)
    }

    // ---- partition: lane holds 16 final bf16 states (8q+e, 32+8q+e). ----
#define BLO(br) __uint_as_float((br) << 16)
#define BHI(br) __uint_as_float((br) & 0xFFFF0000u)
#define PST(NAME, s, pv)                                                     \
    float NAME = fmaf(__log2f(pv) + base2, LN2, trans[STOP_I * K_ + (s)]);
    PST(v0, 8 * q + 0, BLO(b0)) PST(v1, 8 * q + 1, BHI(b0))
    PST(v2, 8 * q + 2, BLO(b1)) PST(v3, 8 * q + 3, BHI(b1))
    PST(v4, 8 * q + 4, BLO(b2)) PST(v5, 8 * q + 5, BHI(b2))
    PST(v6, 8 * q + 6, BLO(b3)) PST(v7, 8 * q + 7, BHI(b3))
    PST(v8, 32 + 8 * q + 0, BLO(b4)) PST(v9, 32 + 8 * q + 1, BHI(b4))
    PST(va, 32 + 8 * q + 2, BLO(b5)) PST(vb, 32 + 8 * q + 3, BHI(b5))
    PST(vc, 32 + 8 * q + 4, BLO(b6)) PST(vd, 32 + 8 * q + 5, BHI(b6))
    PST(ve, 32 + 8 * q + 6, BLO(b7)) PST(vf, 32 + 8 * q + 7, BHI(b7))
#undef PST
    float M = fmaxf(fmaxf(fmaxf(fmaxf(v0, v1), fmaxf(v2, v3)),
                          fmaxf(fmaxf(v4, v5), fmaxf(v6, v7))),
                    fmaxf(fmaxf(fmaxf(v8, v9), fmaxf(va, vb)),
                          fmaxf(fmaxf(vc, vd), fmaxf(ve, vf))));
    M = fmaxf(M, __shfl_xor(M, 16));
    M = fmaxf(M, __shfl_xor(M, 32));
    float sm = exp2f((v0 - M) * LOG2E) + exp2f((v1 - M) * LOG2E)
             + exp2f((v2 - M) * LOG2E) + exp2f((v3 - M) * LOG2E)
             + exp2f((v4 - M) * LOG2E) + exp2f((v5 - M) * LOG2E)
             + exp2f((v6 - M) * LOG2E) + exp2f((v7 - M) * LOG2E)
             + exp2f((v8 - M) * LOG2E) + exp2f((v9 - M) * LOG2E)
             + exp2f((va - M) * LOG2E) + exp2f((vb - M) * LOG2E)
             + exp2f((vc - M) * LOG2E) + exp2f((vd - M) * LOG2E)
             + exp2f((ve - M) * LOG2E) + exp2f((vf - M) * LOG2E);
    sm += __shfl_xor(sm, 16);
    sm += __shfl_xor(sm, 32);
    float part = fmaf(__log2f(sm), LN2, M);

    // ---- gold score: lane covers t = 128*q + c for its column. ----
    float g = 0.0f;
    for (int c = 0; c < 128; ++c) {
        int t = 128 * q + c;
        if (t < lenj) {
            int lt = labels[t * B_ + gb];
            int lp = (t == 0) ? START_I : labels[(t - 1) * B_ + gb];
            g += trans[lt * K_ + lp] + emit[((long)t * B_ + gb) * K_ + lt];
        }
    }
    g += __shfl_xor(g, 16);
    g += __shfl_xor(g, 32);

    if (q == 0) {
        int lastl = labels[(lenj - 1) * B_ + gb];
        g += trans[STOP_I * K_ + lastl];
        out[gb] = part - g;
    }
}

extern "C" void kernel_launch(void* const* d_in, const int* in_sizes, int n_in,
                              void* d_out, int out_size, void* d_ws, size_t ws_size,
                              hipStream_t stream) {
    const float* emit = (const float*)d_in[0];
    const float* trans = (const float*)d_in[1];
    const int* labels = (const int*)d_in[2];
    const float* masks = (const float*)d_in[3];
    float* out = (float*)d_out;
    crf_kernel<<<B_ / 16, 64, 0, stream>>>(emit, trans, labels, masks, out);
}

// Round 9
// 240.145 us; speedup vs baseline: 1.3755x; 1.3755x over previous
//
#include <hip/hip_runtime.h>

namespace {
constexpr int L_ = 512;
constexpr int B_ = 1024;
constexpr int K_ = 64;
constexpr int START_I = 62;
constexpr int STOP_I = 63;
}

__device__ __forceinline__ float bcast0(float x) {
    return __int_as_float(__builtin_amdgcn_readfirstlane(__float_as_int(x)));
}

// broadcast p_{jb+k} (uniform lane index jb+k -> SGPR)
#define RLJ(k) __int_as_float(__builtin_amdgcn_readlane(pi_, jb + (k)))

// One forward-recursion step, linear domain, K split across 2 waves.
// Wave w computes partial_i = sum_{j in [32w,32w+32)} E[i][j] p_j, exchanges
// partials through LDS (double-buffered by PAR), then both waves form
// p'_i = (partA_i + partB_i) * exp(emit_i). EREG = emit loaded 4 steps ago.
// RECEN: rescale by exact power of two from lane0's exponent (proven R2-R5).
#define CRF_STEP(EREG, TNEXT, PAR, RECEN)                                   \
    do {                                                                    \
        float ee = exp2f(EREG * 1.4426950408889634f);                       \
        {                                                                   \
            int tp = (TNEXT) < len ? (TNEXT) : (len - 1);                   \
            EREG = eb[(long)tp * (B_ * K_)];                                \
        }                                                                   \
        int pi_ = __float_as_int(p);                                        \
        float a0 = 0.f, a1 = 0.f, a2 = 0.f, a3 = 0.f;                       \
        a0 = fmaf(RLJ(0),  E0,  a0); a1 = fmaf(RLJ(8),  E8,  a1);           \
        a2 = fmaf(RLJ(16), E16, a2); a3 = fmaf(RLJ(24), E24, a3);           \
        a0 = fmaf(RLJ(1),  E1,  a0); a1 = fmaf(RLJ(9),  E9,  a1);           \
        a2 = fmaf(RLJ(17), E17, a2); a3 = fmaf(RLJ(25), E25, a3);           \
        a0 = fmaf(RLJ(2),  E2,  a0); a1 = fmaf(RLJ(10), E10, a1);           \
        a2 = fmaf(RLJ(18), E18, a2); a3 = fmaf(RLJ(26), E26, a3);           \
        a0 = fmaf(RLJ(3),  E3,  a0); a1 = fmaf(RLJ(11), E11, a1);           \
        a2 = fmaf(RLJ(19), E19, a2); a3 = fmaf(RLJ(27), E27, a3);           \
        a0 = fmaf(RLJ(4),  E4,  a0); a1 = fmaf(RLJ(12), E12, a1);           \
        a2 = fmaf(RLJ(20), E20, a2); a3 = fmaf(RLJ(28), E28, a3);           \
        a0 = fmaf(RLJ(5),  E5,  a0); a1 = fmaf(RLJ(13), E13, a1);           \
        a2 = fmaf(RLJ(21), E21, a2); a3 = fmaf(RLJ(29), E29, a3);           \
        a0 = fmaf(RLJ(6),  E6,  a0); a1 = fmaf(RLJ(14), E14, a1);           \
        a2 = fmaf(RLJ(22), E22, a2); a3 = fmaf(RLJ(30), E30, a3);           \
        a0 = fmaf(RLJ(7),  E7,  a0); a1 = fmaf(RLJ(15), E15, a1);           \
        a2 = fmaf(RLJ(23), E23, a2); a3 = fmaf(RLJ(31), E31, a3);           \
        float mine = (a0 + a1) + (a2 + a3);                                 \
        xbuf[PAR][wid][lane] = mine;                                        \
        __syncthreads();                                                    \
        float pn = (mine + xbuf[PAR][wid ^ 1][lane]) * ee;                  \
        if (RECEN) {                                                        \
            float p0 = bcast0(pn);                                          \
            int kk = (int)(__float_as_uint(p0) >> 23) - 127;                \
            pn *= __uint_as_float((unsigned)(127 - kk) << 23);              \
            base2 += (float)kk;                                             \
        }                                                                   \
        p = pn;                                                             \
    } while (0)

__global__ __launch_bounds__(128, 2)
void crf_kernel(
    const float* __restrict__ emit,    // (L,B,K)
    const float* __restrict__ trans,   // (K,K)
    const int* __restrict__ labels,    // (L,B)
    const float* __restrict__ masks,   // (L,B)
    float* __restrict__ out)           // (B,)
{
    __shared__ float xbuf[2][2][64];   // [parity][wave][state]
    const int lane = threadIdx.x & 63;
    const int wid = threadIdx.x >> 6;
    const int jb = wid << 5;           // this wave's j-half base
    const int b = blockIdx.x;
    constexpr float LOG2E = 1.4426950408889634f;
    constexpr float LN2 = 0.6931471805599453f;

    // E[lane][jb + k], k = 0..31, named scalars, asm-laundered against remat.
    const float* tr = trans + lane * K_ + jb;
#define MKE(q, A, Bn, C, D)                                                 \
    float A  = exp2f(tr[4 * (q) + 0] * LOG2E);                              \
    float Bn = exp2f(tr[4 * (q) + 1] * LOG2E);                              \
    float C  = exp2f(tr[4 * (q) + 2] * LOG2E);                              \
    float D  = exp2f(tr[4 * (q) + 3] * LOG2E);                              \
    asm("" : "+v"(A), "+v"(Bn), "+v"(C), "+v"(D));
    MKE(0, E0,  E1,  E2,  E3)   MKE(1, E4,  E5,  E6,  E7)
    MKE(2, E8,  E9,  E10, E11)  MKE(3, E12, E13, E14, E15)
    MKE(4, E16, E17, E18, E19)  MKE(5, E20, E21, E22, E23)
    MKE(6, E24, E25, E26, E27)  MKE(7, E28, E29, E30, E31)
#undef MKE

    // len[b] = sum_t masks[t,b]  (masks are prefix masks; per-wave reduce)
    int len = 0;
    #pragma unroll
    for (int c = 0; c < L_ / 64; ++c)
        len += (int)masks[(c * 64 + lane) * B_ + b];
    #pragma unroll
    for (int off = 32; off >= 1; off >>= 1)
        len += __shfl_xor(len, off);

    // Linear-domain state (replicated in both waves): lane i holds p_i.
    float p = (lane == START_I) ? 1.0f : 0.0f;
    float base2 = 0.0f;
    const float* eb = emit + b * K_ + lane;

    // 4-deep emit prefetch ring (len >= 128 always; depth proven in R5/R6).
    float e0 = eb[0L * (B_ * K_)];
    float e1 = eb[1L * (B_ * K_)];
    float e2 = eb[2L * (B_ * K_)];
    float e3 = eb[3L * (B_ * K_)];

    int t = 0;
    for (; t + 4 <= len; t += 4) {
        CRF_STEP(e0, t + 4, 0, 0);
        CRF_STEP(e1, t + 5, 1, 0);
        CRF_STEP(e2, t + 6, 0, 0);
        CRF_STEP(e3, t + 7, 1, 1);
    }
    if (t < len) { CRF_STEP(e0, len - 1, 0, 1); ++t; }
    if (t < len) { CRF_STEP(e1, len - 1, 1, 1); ++t; }
    if (t < len) { CRF_STEP(e2, len - 1, 0, 1); ++t; }

    // partition = LSE_k(score_k + T[STOP,k])  (computed redundantly by both
    // waves; no barriers below, so divergence between waves is safe)
    float v = fmaf(__log2f(p) + base2, LN2, trans[STOP_I * K_ + lane]);
    float M = v;
    #pragma unroll
    for (int off = 32; off >= 1; off >>= 1)
        M = fmaxf(M, __shfl_xor(M, off));
    float pe = exp2f((v - M) * LOG2E);
    #pragma unroll
    for (int off = 32; off >= 1; off >>= 1)
        pe += __shfl_xor(pe, off);
    float part = fmaf(__log2f(pe), LN2, M);

    if (wid == 0) {
        // gold score: lanes cover t = c*64 + lane
        float g = 0.0f;
        #pragma unroll
        for (int c = 0; c < L_ / 64; ++c) {
            int tt = c * 64 + lane;
            if (tt < len) {
                int lt = labels[tt * B_ + b];
                int lp = (tt == 0) ? START_I : labels[(tt - 1) * B_ + b];
                g += trans[lt * K_ + lp] + emit[((long)tt * B_ + b) * K_ + lt];
            }
        }
        #pragma unroll
        for (int off = 32; off >= 1; off >>= 1)
            g += __shfl_xor(g, off);
        int lastl = labels[(len - 1) * B_ + b];
        g += trans[STOP_I * K_ + lastl];

        if (lane == 0) out[b] = part - g;
    }
}

extern "C" void kernel_launch(void* const* d_in, const int* in_sizes, int n_in,
                              void* d_out, int out_size, void* d_ws, size_t ws_size,
                              hipStream_t stream) {
    const float* emit = (const float*)d_in[0];
    const float* trans = (const float*)d_in[1];
    const int* labels = (const int*)d_in[2];
    const float* masks = (const float*)d_in[3];
    float* out = (float*)d_out;
    crf_kernel<<<B_, 128, 0, stream>>>(emit, trans, labels, masks, out);
}

// Round 10
// 134.274 us; speedup vs baseline: 2.4601x; 1.7885x over previous
//
#include <hip/hip_runtime.h>

namespace {
constexpr int L_ = 512;
constexpr int B_ = 1024;
constexpr int K_ = 64;
constexpr int START_I = 62;
constexpr int STOP_I = 63;
}

__device__ __forceinline__ float bcast0(float x) {
    return __int_as_float(__builtin_amdgcn_readfirstlane(__float_as_int(x)));
}

#define SB __builtin_amdgcn_sched_barrier(0);

// One v_readlane as its own volatile asm: declares s_J and fills it from
// lane J of p. Volatile asms keep their mutual program order.
#define RLD(J)                                                              \
    float s_##J;                                                            \
    asm volatile("v_readlane_b32 %0, %1, " #J : "=s"(s_##J) : "v"(p));

#define RLG_A RLD(0)  RLD(1)  RLD(2)  RLD(3)  RLD(4)  RLD(5)  RLD(6)  RLD(7) \
              RLD(8)  RLD(9)  RLD(10) RLD(11) RLD(12) RLD(13) RLD(14) RLD(15)
#define RLG_B RLD(16) RLD(17) RLD(18) RLD(19) RLD(20) RLD(21) RLD(22) RLD(23) \
              RLD(24) RLD(25) RLD(26) RLD(27) RLD(28) RLD(29) RLD(30) RLD(31)
#define RLG_C RLD(32) RLD(33) RLD(34) RLD(35) RLD(36) RLD(37) RLD(38) RLD(39) \
              RLD(40) RLD(41) RLD(42) RLD(43) RLD(44) RLD(45) RLD(46) RLD(47)
#define RLG_D RLD(48) RLD(49) RLD(50) RLD(51) RLD(52) RLD(53) RLD(54) RLD(55) \
              RLD(56) RLD(57) RLD(58) RLD(59) RLD(60) RLD(61) RLD(62) RLD(63)

#define FM(J, ACC) ACC = fmaf(s_##J, E##J, ACC);
#define FMG(J0, J1, J2, J3, J4, J5, J6, J7,                                 \
            J8, J9, J10, J11, J12, J13, J14, J15)                           \
    FM(J0, a0)  FM(J1, a1)  FM(J2, a2)  FM(J3, a3)                          \
    FM(J4, a0)  FM(J5, a1)  FM(J6, a2)  FM(J7, a3)                          \
    FM(J8, a0)  FM(J9, a1)  FM(J10, a2) FM(J11, a3)                         \
    FM(J12, a0) FM(J13, a1) FM(J14, a2) FM(J15, a3)
#define FMG_A FMG(0,1,2,3,4,5,6,7,8,9,10,11,12,13,14,15)
#define FMG_B FMG(16,17,18,19,20,21,22,23,24,25,26,27,28,29,30,31)
#define FMG_C FMG(32,33,34,35,36,37,38,39,40,41,42,43,44,45,46,47)
#define FMG_D FMG(48,49,50,51,52,53,54,55,56,57,58,59,60,61,62,63)

// One forward-recursion step, linear domain:
// p'_i = (sum_j E[i][j] p_j) * exp(emit_i). EREG = emit loaded 4 steps ago.
// Forced schedule: every fmac's SGPR operand was written >=16 insts earlier
// (sched_barrier(0)-fenced regions), eliminating SGPR-read wait-states.
#define CRF_STEP(EREG, TNEXT, RECEN)                                        \
    do {                                                                    \
        float ee = exp2f(EREG * 1.4426950408889634f);                       \
        {                                                                   \
            int tp = (TNEXT) < len ? (TNEXT) : (len - 1);                   \
            EREG = eb[(long)tp * (B_ * K_)];                                \
        }                                                                   \
        float a0 = 0.f, a1 = 0.f, a2 = 0.f, a3 = 0.f;                       \
        RLG_A RLG_B                                                         \
        SB                                                                  \
        FMG_A RLG_C                                                         \
        SB                                                                  \
        FMG_B RLG_D                                                         \
        SB                                                                  \
        FMG_C                                                               \
        SB                                                                  \
        FMG_D                                                               \
        float pn = ((a0 + a1) + (a2 + a3)) * ee;                            \
        if (RECEN) {                                                        \
            float p0 = bcast0(pn);                                          \
            int kk = (int)(__float_as_uint(p0) >> 23) - 127;                \
            pn *= __uint_as_float((unsigned)(127 - kk) << 23);              \
            base2 += (float)kk;                                             \
        }                                                                   \
        p = pn;                                                             \
    } while (0)

__global__ __launch_bounds__(64)
__attribute__((amdgpu_waves_per_eu(1, 1)))
void crf_kernel(
    const float* __restrict__ emit,    // (L,B,K)
    const float* __restrict__ trans,   // (K,K)
    const int* __restrict__ labels,    // (L,B)
    const float* __restrict__ masks,   // (L,B)
    float* __restrict__ out)           // (B,)
{
    const int lane = threadIdx.x & 63;
    const int b = blockIdx.x;
    constexpr float LOG2E = 1.4426950408889634f;
    constexpr float LN2 = 0.6931471805599453f;

    // E row `lane` of exp(T) in 64 named scalars (VGPR-resident per R5:
    // VGPR_Count 132, asm-laundered against remat).
    const float4* t4 = reinterpret_cast<const float4*>(trans + lane * K_);
#define MKE(q, A, Bn, C, D)                                                 \
    float4 tv##q = t4[q];                                                   \
    float A  = exp2f(tv##q.x * LOG2E);                                      \
    float Bn = exp2f(tv##q.y * LOG2E);                                      \
    float C  = exp2f(tv##q.z * LOG2E);                                      \
    float D  = exp2f(tv##q.w * LOG2E);                                      \
    asm("" : "+v"(A), "+v"(Bn), "+v"(C), "+v"(D));
    MKE(0,  E0,  E1,  E2,  E3)   MKE(1,  E4,  E5,  E6,  E7)
    MKE(2,  E8,  E9,  E10, E11)  MKE(3,  E12, E13, E14, E15)
    MKE(4,  E16, E17, E18, E19)  MKE(5,  E20, E21, E22, E23)
    MKE(6,  E24, E25, E26, E27)  MKE(7,  E28, E29, E30, E31)
    MKE(8,  E32, E33, E34, E35)  MKE(9,  E36, E37, E38, E39)
    MKE(10, E40, E41, E42, E43)  MKE(11, E44, E45, E46, E47)
    MKE(12, E48, E49, E50, E51)  MKE(13, E52, E53, E54, E55)
    MKE(14, E56, E57, E58, E59)  MKE(15, E60, E61, E62, E63)
#undef MKE

    // len[b] = sum_t masks[t,b]  (masks are prefix masks)
    int len = 0;
    #pragma unroll
    for (int c = 0; c < L_ / 64; ++c)
        len += (int)masks[(c * 64 + lane) * B_ + b];
    #pragma unroll
    for (int off = 32; off >= 1; off >>= 1)
        len += __shfl_xor(len, off);

    // Linear-domain state: score_i = (log2 p_i + base2)*ln2.
    float p = (lane == START_I) ? 1.0f : 0.0f;
    float base2 = 0.0f;
    const float* eb = emit + b * K_ + lane;

    // 4-deep emit prefetch ring (depth proven sufficient in R5/R6).
    float e0 = eb[0L * (B_ * K_)];
    float e1 = eb[1L * (B_ * K_)];
    float e2 = eb[2L * (B_ * K_)];
    float e3 = eb[3L * (B_ * K_)];

    int t = 0;
    for (; t + 4 <= len; t += 4) {
        CRF_STEP(e0, t + 4, 0);
        CRF_STEP(e1, t + 5, 0);
        CRF_STEP(e2, t + 6, 0);
        CRF_STEP(e3, t + 7, 1);
    }
    if (t < len) { CRF_STEP(e0, len - 1, 1); ++t; }
    if (t < len) { CRF_STEP(e1, len - 1, 1); ++t; }
    if (t < len) { CRF_STEP(e2, len - 1, 1); ++t; }

    // partition = LSE_k(score_k + T[STOP,k])
    float v = fmaf(__log2f(p) + base2, LN2, trans[STOP_I * K_ + lane]);
    float M = v;
    #pragma unroll
    for (int off = 32; off >= 1; off >>= 1)
        M = fmaxf(M, __shfl_xor(M, off));
    float pe = exp2f((v - M) * LOG2E);
    #pragma unroll
    for (int off = 32; off >= 1; off >>= 1)
        pe += __shfl_xor(pe, off);
    float part = fmaf(__log2f(pe), LN2, M);

    // gold score: lanes cover t = c*64 + lane
    float g = 0.0f;
    #pragma unroll
    for (int c = 0; c < L_ / 64; ++c) {
        int tt = c * 64 + lane;
        if (tt < len) {
            int lt = labels[tt * B_ + b];
            int lp = (tt == 0) ? START_I : labels[(tt - 1) * B_ + b];
            g += trans[lt * K_ + lp] + emit[((long)tt * B_ + b) * K_ + lt];
        }
    }
    #pragma unroll
    for (int off = 32; off >= 1; off >>= 1)
        g += __shfl_xor(g, off);
    int lastl = labels[(len - 1) * B_ + b];
    g += trans[STOP_I * K_ + lastl];

    if (lane == 0) out[b] = part - g;
}

extern "C" void kernel_launch(void* const* d_in, const int* in_sizes, int n_in,
                              void* d_out, int out_size, void* d_ws, size_t ws_size,
                              hipStream_t stream) {
    const float* emit = (const float*)d_in[0];
    const float* trans = (const float*)d_in[1];
    const int* labels = (const int*)d_in[2];
    const float* masks = (const float*)d_in[3];
    float* out = (float*)d_out;
    crf_kernel<<<B_, 64, 0, stream>>>(emit, trans, labels, masks, out);
}